// Round 12
// baseline (108.657 us; speedup 1.0000x reference)
//
#include <hip/hip_runtime.h>
#include <math.h>

// ---------------------------------------------------------------------------
// OBB CIoU loss, N independent box pairs -> scalar mean.
// R12: two counter-validated cuts on R11 (41.8 us kernel):
//  (a) float2 LDS payload (drop bf16 pack/unpack, ~-110 VALU/pair). R9 proved
//      occupancy >4 blocks/CU buys nothing, so the 34.8 KB slab is free; R6's
//      counters showed the float2 slab has ~0 bank conflicts (dword slab:826k).
//  (b) masked-array shoelace: 2 cndmask/vertex (not 4) + 2 fma accumulate
//      (~-60 VALU/pair).
// Carried: pk-f32 vector math + atan-difference identity (R11), packed-uint
// key Batcher sort + LDS gather (R6), 16-vertex compacted candidates (R4),
// diamond pseudo-angle + frcp (R3/R6), native sin/cos (R5), PAIRS=2 full
// unroll (R9/R10), exact-reference semantics.
// ---------------------------------------------------------------------------

#define BLOCK 256
#define NV 16
#define PAIRS 2
#define LDS_STRIDE 17   // 16 float2 slots + 1 pad (odd stride, ~0 conflicts R6)

typedef float v2f __attribute__((ext_vector_type(2)));

// --- compile-time Batcher odd-even mergesort network for n=16 ---
struct CEList {
    int n;
    unsigned char lo[128];
    unsigned char hi[128];
};

constexpr CEList make_ces16() {
    CEList L{};
    L.n = 0;
    for (int p = 1; p < NV; p <<= 1)
        for (int k = p; k >= 1; k >>= 1)
            for (int j = k % p; j + k < NV; j += 2 * k)
                for (int i = 0; i < k; i++) {
                    int lo = i + j, hi = i + j + k;
                    if (hi < NV && (lo / (2 * p)) == (hi / (2 * p))) {
                        L.lo[L.n] = (unsigned char)lo;
                        L.hi[L.n] = (unsigned char)hi;
                        L.n++;
                    }
                }
    return L;
}

constexpr CEList CES = make_ces16();

__device__ __forceinline__ float frcp(float x) {
    return __builtin_amdgcn_rcpf(x);
}

__device__ __forceinline__ v2f splat2(float x) {
    v2f r; r.x = x; r.y = x; return r;
}

__device__ __forceinline__ float hadd2(v2f v) { return v.x + v.y; }

// Diamond pseudo-angle, no wrap: range [0,4), a cyclic shift of atan2 order.
// Cyclic shoelace is shift-invariant. All values nonneg -> uint-monotone.
__device__ __forceinline__ float angle_key(float x, float y) {
    float ax = fabsf(x), ay = fabsf(y);
    float den = ax + ay;
    float r = x * frcp(den);
    r = (den > 0.f) ? r : 0.f;
    return (y >= 0.f) ? (1.f - r) : (3.f + r);
}

// atan(z) for z in [0,1]: degree-11 odd minimax, max err ~1.5e-5 rad.
__device__ __forceinline__ float atan01(float z) {
    float z2 = z * z;
    float p = -0.01172120f;
    p = p * z2 + 0.05265332f;
    p = p * z2 - 0.11643287f;
    p = p * z2 + 0.19354346f;
    p = p * z2 - 0.33262347f;
    p = p * z2 + 0.99997726f;
    return z * p;
}

__device__ __forceinline__ float pair_loss(const float* __restrict__ p,
                                           const float* __restrict__ t,
                                           float wv, v2f* __restrict__ myb)
{
    const float EPSf  = 1e-8f;   // segment-intersection eps (reference EPS)
    const float TOLf  = 1e-6f;   // box_in_box tol
    const float MEPS  = 1e-6f;   // MODE_EPS
    const float PIf   = 3.14159265358979323846f;

    float pcx = p[0], pcy = p[1], pw = p[2], ph = p[3], pa = p[4];
    float tcx = t[0], tcy = t[1], tw = t[2], th = t[3], ta = t[4];

    // ---- corners (packed) ---- (|angles| bounded: native sin/cos OK)
    float ca = __cosf(pa), sa = __sinf(pa);
    float cb = __cosf(ta), sb = __sinf(ta);
    v2f C1[4], C2[4];
    {
        const float xs[4] = { 0.5f, -0.5f, -0.5f, 0.5f };
        const float ys[4] = { -0.5f, -0.5f, 0.5f, 0.5f };
        v2f R1x = { ca, sa }, R1y = { -sa, ca };
        v2f R2x = { cb, sb }, R2y = { -sb, cb };
        v2f CT1 = { pcx, pcy }, CT2 = { tcx, tcy };
        #pragma unroll
        for (int k = 0; k < 4; k++) {
            float x4 = xs[k] * pw, y4 = ys[k] * ph;
            C1[k] = splat2(x4) * R1x + splat2(y4) * R1y + CT1;
            float x4b = xs[k] * tw, y4b = ys[k] * th;
            C2[k] = splat2(x4b) * R2x + splat2(y4b) * R2y + CT2;
        }
    }

    // ---- 16 candidate vertices + validity masks ----
    v2f  V[NV];
    bool msk[NV];

    // corners1 inside box2  (verts 0..3)
    {
        v2f A  = C2[0];
        v2f AB = C2[1] - A, AD = C2[3] - A;
        float rab = frcp(hadd2(AB * AB));
        float rad = frcp(hadd2(AD * AD));
        #pragma unroll
        for (int k = 0; k < 4; k++) {
            v2f AM = C1[k] - A;
            float pab = hadd2(AB * AM) * rab;
            float pad = hadd2(AD * AM) * rad;
            msk[k] = (pab > -TOLf) && (pab < 1.f + TOLf) &&
                     (pad > -TOLf) && (pad < 1.f + TOLf);
            V[k] = C1[k];
        }
    }
    // corners2 inside box1  (verts 4..7)
    {
        v2f A  = C1[0];
        v2f AB = C1[1] - A, AD = C1[3] - A;
        float rab = frcp(hadd2(AB * AB));
        float rad = frcp(hadd2(AD * AD));
        #pragma unroll
        for (int k = 0; k < 4; k++) {
            v2f AM = C2[k] - A;
            float pab = hadd2(AB * AM) * rab;
            float pad = hadd2(AD * AM) * rad;
            msk[4 + k] = (pab > -TOLf) && (pab < 1.f + TOLf) &&
                         (pad > -TOLf) && (pad < 1.f + TOLf);
            V[4 + k] = C2[k];
        }
    }
    // edge x edge intersections, compacted 4 -> 2 per box1 edge
    #pragma unroll
    for (int e1 = 0; e1 < 4; e1++) {
        v2f P1 = C1[e1];
        v2f E  = C1[(e1 + 1) & 3] - P1;
        v2f  Q[4];
        bool qm[4];
        #pragma unroll
        for (int e2 = 0; e2 < 4; e2++) {
            v2f P3 = C2[e2];
            v2f F  = C2[(e2 + 1) & 3] - P3;
            float num  = F.y * E.x - F.x * E.y;
            float rnum = frcp(num + EPSf);
            v2f D = P1 - P3;
            float den_t = F.x * D.y - F.y * D.x;
            float den_u = E.x * D.y - E.y * D.x;
            float tt = den_t * rnum;
            float uu = -den_u * rnum;
            qm[e2] = (num != 0.f) && (tt > 0.f) && (tt < 1.f)
                                  && (uu > 0.f) && (uu < 1.f);
            Q[e2] = splat2(tt) * E + P1;
        }
        bool mfL = qm[0] || qm[1];
        v2f  fL  = qm[0] ? Q[0] : Q[1];
        bool msL = qm[0] && qm[1];
        bool mfR = qm[2] || qm[3];
        v2f  fR  = qm[2] ? Q[2] : Q[3];
        bool msR = qm[2] && qm[3];
        int s0 = 8 + 2 * e1, s1 = s0 + 1;
        V[s0]   = mfL ? fL : fR;
        msk[s0] = mfL || mfR;
        v2f  t2 = msL ? Q[1] : fR;
        V[s1]   = mfL ? t2 : Q[3];
        msk[s1] = msL || (mfL && mfR) || msR;
    }

    // ---- centroid of valid verts ----
    v2f s2 = { 0.f, 0.f };
    float cnt = 0.f;
    const v2f Z2 = { 0.f, 0.f };
    #pragma unroll
    for (int k = 0; k < NV; k++) {
        s2  += msk[k] ? V[k] : Z2;
        cnt += msk[k] ? 1.f : 0.f;
    }
    float rden = frcp(fmaxf(cnt, 1.f));
    v2f cen = s2 * splat2(rden);

    // ---- relative coords -> LDS scatter (float2) + packed key (key|slot) ----
    unsigned int ku[NV];
    #pragma unroll
    for (int k = 0; k < NV; k++) {
        v2f R = V[k] - cen;
        myb[k] = R;
        float a = msk[k] ? angle_key(R.x, R.y) : 1e7f;
        ku[k] = (__float_as_uint(a) & 0xFFFFFFF0u) | (unsigned int)k;
    }

    // ---- sort 16 packed keys (Batcher network, 2 VALU per CE) ----
    #pragma unroll
    for (int c = 0; c < CES.n; c++) {
        const int lo = CES.lo[c], hi = CES.hi[c];
        unsigned int a = ku[lo], b = ku[hi];
        ku[lo] = a < b ? a : b;
        ku[hi] = a < b ? b : a;
    }

    // ---- gather payload by sorted index; masked-array shoelace ----
    const unsigned int VALID_LIM = 0x49742400u;  // bits of 1e6f
    v2f G[NV];
    #pragma unroll
    for (int k = 0; k < NV; k++)
        G[k] = myb[ku[k] & 15u];
    // invalid slots (sorted to end) -> first vertex, ONCE (2 cndmask/vertex)
    v2f F0 = G[0];
    #pragma unroll
    for (int k = 1; k < NV; k++)
        G[k] = (ku[k] < VALID_LIM) ? G[k] : F0;
    float cross = 0.f;
    #pragma unroll
    for (int k = 0; k < NV; k++) {
        int kn = (k + 1) % NV;           // constant after unroll
        cross = fmaf(G[k].x, G[kn].y, cross);
        cross = fmaf(-G[k].y, G[kn].x, cross);
    }
    float inter = fabsf(cross) * 0.5f;

    // ---- CIoU ----
    float area1 = pw * ph, area2 = tw * th;
    float iou = inter * frcp(area1 + area2 - inter);
    iou = fminf(fmaxf(iou, 0.f), 1.f);

    float cA = fabsf(ca), sA = fabsf(sa);
    float cB = fabsf(cb), sB = fabsf(sb);
    float dw1 = (pw * cA + ph * sA) * 0.5f, dh1 = (pw * sA + ph * cA) * 0.5f;
    float dw2 = (tw * cB + th * sB) * 0.5f, dh2 = (tw * sB + th * cB) * 0.5f;
    float hp0 = pcx - dw1, hp1 = pcy - dh1, hp2 = pcx + dw1, hp3 = pcy + dh1;
    float ht0 = tcx - dw2, ht1 = tcy - dh2, ht2 = tcx + dw2, ht3 = tcy + dh2;

    float enw = fmaxf(fmaxf(hp2, ht2) - fminf(hp0, ht0), 0.f);
    float enh = fmaxf(fmaxf(hp3, ht3) - fminf(hp1, ht1), 0.f);
    float c2v = enw * enw + enh * enh + MEPS;
    float rho2 = (tcx - pcx) * (tcx - pcx) + (tcy - pcy) * (tcy - pcy);

    // atan(r1)-atan(r2) = atan((r1-r2)/(1+r1*r2)); dv squared -> sign-free.
    float factor = 4.f / (PIf * PIf);
    float r1 = tw * frcp(th + MEPS);
    float r2 = pw * frcp(ph + MEPS);
    float xd = (r1 - r2) * frcp(1.f + r1 * r2);
    float axd = fabsf(xd);
    bool  big = axd > 1.f;
    float z   = big ? frcp(axd) : axd;
    float at  = atan01(z);
    float dv  = big ? ((0.5f * PIf) - at) : at;
    float v_ = factor * dv * dv;
    float alpha = (iou > 0.5f) ? v_ * frcp(1.f - iou + v_ + MEPS) : 0.f;

    float rhoterm = fminf(fmaxf(rho2 * frcp(c2v), 0.f), 1.f);
    float ciou = iou - (rhoterm + alpha * v_);
    return (1.f - ciou) * wv;
}

__global__ __launch_bounds__(BLOCK)
void obb_ciou_kernel(const float* __restrict__ pred,
                     const float* __restrict__ tgt,
                     const float* __restrict__ wgt,
                     float* __restrict__ out,
                     int N, float invN)
{
    __shared__ v2f slab[BLOCK * LDS_STRIDE];
    v2f* myb = slab + (int)threadIdx.x * LDS_STRIDE;

    int blk0 = blockIdx.x * (BLOCK * PAIRS);
    float loss = 0.f;

    #pragma unroll
    for (int u = 0; u < PAIRS; u++) {
        int i = blk0 + u * BLOCK + (int)threadIdx.x;
        if (i < N)
            loss += pair_loss(pred + (size_t)i * 5, tgt + (size_t)i * 5,
                              wgt[i], myb);
    }

    // ---- reduction: wave shuffle -> LDS -> one atomic per block ----
    #pragma unroll
    for (int off = 32; off > 0; off >>= 1)
        loss += __shfl_down(loss, off, 64);

    __shared__ float red[BLOCK / 64];
    int wave = threadIdx.x >> 6;
    int lane = threadIdx.x & 63;
    if (lane == 0) red[wave] = loss;
    __syncthreads();
    if (threadIdx.x == 0) {
        float s = 0.f;
        #pragma unroll
        for (int w = 0; w < BLOCK / 64; w++) s += red[w];
        atomicAdd(out, s * invN);
    }
}

extern "C" void kernel_launch(void* const* d_in, const int* in_sizes, int n_in,
                              void* d_out, int out_size, void* d_ws, size_t ws_size,
                              hipStream_t stream) {
    const float* pred = (const float*)d_in[0];
    const float* tgt  = (const float*)d_in[1];
    const float* wgt  = (const float*)d_in[2];
    float* out = (float*)d_out;
    int N = in_sizes[2];  // weight element count == N boxes

    hipMemsetAsync(out, 0, sizeof(float) * (size_t)out_size, stream);

    int grid = (N + BLOCK * PAIRS - 1) / (BLOCK * PAIRS);
    obb_ciou_kernel<<<grid, BLOCK, 0, stream>>>(pred, tgt, wgt, out, N,
                                                1.f / (float)N);
}